// Round 1
// baseline (1175.601 us; speedup 1.0000x reference)
//
#include <hip/hip_runtime.h>
#include <math.h>

#define N_NODES 50000
#define N_EDGES 800000
#define ETOT (N_EDGES + N_NODES)
#define F_IN 128
#define HD 64
#define NHEAD 4
#define HC 256
#define NGRAPH 512
#define NOUT 64
#define LN_EPS 1e-5f

__device__ __forceinline__ float wave_sum(float v) {
#pragma unroll
    for (int m = 1; m < 64; m <<= 1) v += __shfl_xor(v, m, 64);
    return v;
}
__device__ __forceinline__ float wave_max(float v) {
#pragma unroll
    for (int m = 1; m < 64; m <<= 1) v = fmaxf(v, __shfl_xor(v, m, 64));
    return v;
}
__device__ __forceinline__ float gelu_exact(float x) {
    return 0.5f * x * (1.0f + erff(x * 0.70710678118654752f));
}

// ---------------- CSR build ----------------
__global__ void k_count(const int* __restrict__ ei, int* __restrict__ deg) {
    int t = blockIdx.x * blockDim.x + threadIdx.x;
    if (t >= ETOT) return;
    int dst = (t < N_EDGES) ? ei[N_EDGES + t] : (t - N_EDGES);
    atomicAdd(deg + dst, 1);
}

__global__ void k_scan(const int* __restrict__ deg, int* __restrict__ rowptr,
                       int* __restrict__ cursor) {
    __shared__ int buf[1024];
    __shared__ int carry;
    if (threadIdx.x == 0) { carry = 0; rowptr[0] = 0; }
    __syncthreads();
    for (int base = 0; base < N_NODES; base += 1024) {
        int i = base + threadIdx.x;
        int v = (i < N_NODES) ? deg[i] : 0;
        buf[threadIdx.x] = v;
        __syncthreads();
        for (int off = 1; off < 1024; off <<= 1) {
            int t = (threadIdx.x >= off) ? buf[threadIdx.x - off] : 0;
            __syncthreads();
            buf[threadIdx.x] += t;
            __syncthreads();
        }
        if (i < N_NODES) {
            int incl = carry + buf[threadIdx.x];
            rowptr[i + 1] = incl;
            cursor[i] = incl - v;   // exclusive start, doubles as fill cursor
        }
        __syncthreads();
        if (threadIdx.x == 1023) carry += buf[1023];
        __syncthreads();
    }
}

__global__ void k_fill(const int* __restrict__ ei, int* __restrict__ cursor,
                       int* __restrict__ csr) {
    int t = blockIdx.x * blockDim.x + threadIdx.x;
    if (t >= ETOT) return;
    int src, dst;
    if (t < N_EDGES) { src = ei[t]; dst = ei[N_EDGES + t]; }
    else             { src = t - N_EDGES; dst = src; }
    int p = atomicAdd(cursor + dst, 1);
    csr[p] = src;
}

// ---------------- input projection: concat -> linear(192->64) -> LN -> GELU ----------------
__global__ void k_proj_in(const float* __restrict__ x, const int* __restrict__ gid,
                          const float* __restrict__ gt, const float* __restrict__ inW,
                          const float* __restrict__ inb, const float* __restrict__ lng,
                          const float* __restrict__ lnb, float* __restrict__ h0) {
    __shared__ float row[4][192];
    int wid = threadIdx.x >> 6, lane = threadIdx.x & 63;
    int node = blockIdx.x * 4 + wid;
    row[wid][lane]        = x[node * F_IN + lane];
    row[wid][64 + lane]   = x[node * F_IN + 64 + lane];
    int g = gid[node];
    row[wid][128 + lane]  = gt[g * HD + lane];
    __syncthreads();
    float acc = inb[lane];
#pragma unroll 4
    for (int k = 0; k < 192; k++) acc += row[wid][k] * inW[k * 64 + lane];
    float mu = wave_sum(acc) * (1.0f / 64.0f);
    float d = acc - mu;
    float var = wave_sum(d * d) * (1.0f / 64.0f);
    float y = d * rsqrtf(var + LN_EPS) * lng[lane] + lnb[lane];
    h0[node * HD + lane] = gelu_exact(y);
}

// ---------------- per-layer projection: xl = A @ W, plus attention logits ----------------
template <int K>
__global__ void k_proj_gat(const float* __restrict__ A, const float* __restrict__ W,
                           const float* __restrict__ as_, const float* __restrict__ ad_,
                           float* __restrict__ xl, float* __restrict__ als,
                           float* __restrict__ ald) {
    __shared__ float arow[4][K];
    int wid = threadIdx.x >> 6, lane = threadIdx.x & 63;
    int node = blockIdx.x * 4 + wid;
#pragma unroll
    for (int k = lane; k < K; k += 64) arow[wid][k] = A[node * K + k];
    __syncthreads();
    const float4* W4 = (const float4*)W;
    float4 acc = {0.f, 0.f, 0.f, 0.f};
#pragma unroll 4
    for (int k = 0; k < K; k++) {
        float a = arow[wid][k];
        float4 w = W4[k * 64 + lane];
        acc.x += a * w.x; acc.y += a * w.y; acc.z += a * w.z; acc.w += a * w.w;
    }
    ((float4*)xl)[node * 64 + lane] = acc;
    int head = lane >> 4;
    const float4* as4 = (const float4*)as_;
    const float4* ad4 = (const float4*)ad_;
    float4 sv = as4[head * 16 + (lane & 15)];
    float4 dv = ad4[head * 16 + (lane & 15)];
    float ps = acc.x * sv.x + acc.y * sv.y + acc.z * sv.z + acc.w * sv.w;
    float pd = acc.x * dv.x + acc.y * dv.y + acc.z * dv.z + acc.w * dv.w;
#pragma unroll
    for (int m = 1; m < 16; m <<= 1) {
        ps += __shfl_xor(ps, m, 64);
        pd += __shfl_xor(pd, m, 64);
    }
    if ((lane & 15) == 0) { als[node * 4 + head] = ps; ald[node * 4 + head] = pd; }
}

// ---------------- GAT aggregation (pull, one wave per dst) + fused epilogue ----------------
template <int LAYER>
__global__ void k_gat_agg(const int* __restrict__ rowptr, const int* __restrict__ csr,
                          const float* __restrict__ xl, const float* __restrict__ als,
                          const float* __restrict__ ald, const float* __restrict__ bias,
                          const float* __restrict__ lng, const float* __restrict__ lnb,
                          const float* __restrict__ identity, float* __restrict__ out,
                          const int* __restrict__ batch, float* __restrict__ pooled,
                          int* __restrict__ cnt) {
    int wid = threadIdx.x >> 6, lane = threadIdx.x & 63;
    int node = blockIdx.x * 4 + wid;
    int start = rowptr[node], end = rowptr[node + 1];
    int head = lane >> 4;
    float4 adv = ((const float4*)ald)[node];
    float ad0 = adv.x, ad1 = adv.y, ad2 = adv.z, ad3 = adv.w;
    float m0 = -1e30f, m1 = -1e30f, m2 = -1e30f, m3 = -1e30f;
    float s0 = 0.f, s1 = 0.f, s2 = 0.f, s3 = 0.f;
    // pass 1: online softmax stats per head, lanes strided over edges
    for (int k = start + lane; k < end; k += 64) {
        int sn = csr[k];
        float4 sv = ((const float4*)als)[sn];
        float e0 = sv.x + ad0; e0 = fmaxf(e0, 0.2f * e0);
        float e1 = sv.y + ad1; e1 = fmaxf(e1, 0.2f * e1);
        float e2 = sv.z + ad2; e2 = fmaxf(e2, 0.2f * e2);
        float e3 = sv.w + ad3; e3 = fmaxf(e3, 0.2f * e3);
        float n;
        n = fmaxf(m0, e0); s0 = s0 * __expf(m0 - n) + __expf(e0 - n); m0 = n;
        n = fmaxf(m1, e1); s1 = s1 * __expf(m1 - n) + __expf(e1 - n); m1 = n;
        n = fmaxf(m2, e2); s2 = s2 * __expf(m2 - n) + __expf(e2 - n); m2 = n;
        n = fmaxf(m3, e3); s3 = s3 * __expf(m3 - n) + __expf(e3 - n); m3 = n;
    }
#pragma unroll
    for (int msk = 1; msk < 64; msk <<= 1) {
        float o, t, n;
        o = __shfl_xor(m0, msk, 64); t = __shfl_xor(s0, msk, 64);
        n = fmaxf(m0, o); s0 = s0 * __expf(m0 - n) + t * __expf(o - n); m0 = n;
        o = __shfl_xor(m1, msk, 64); t = __shfl_xor(s1, msk, 64);
        n = fmaxf(m1, o); s1 = s1 * __expf(m1 - n) + t * __expf(o - n); m1 = n;
        o = __shfl_xor(m2, msk, 64); t = __shfl_xor(s2, msk, 64);
        n = fmaxf(m2, o); s2 = s2 * __expf(m2 - n) + t * __expf(o - n); m2 = n;
        o = __shfl_xor(m3, msk, 64); t = __shfl_xor(s3, msk, 64);
        n = fmaxf(m3, o); s3 = s3 * __expf(m3 - n) + t * __expf(o - n); m3 = n;
    }
    float mh  = head == 0 ? m0 : head == 1 ? m1 : head == 2 ? m2 : m3;
    float sh  = head == 0 ? s0 : head == 1 ? s1 : head == 2 ? s2 : s3;
    float adh = head == 0 ? ad0 : head == 1 ? ad1 : head == 2 ? ad2 : ad3;
    float invh = 1.0f / (sh + 1e-16f);
    // pass 2: weighted accumulation; lane owns 4 contiguous features
    float4 acc = {0.f, 0.f, 0.f, 0.f};
    for (int k = start; k < end; k++) {
        int sn = csr[k];
        float e = als[sn * 4 + head] + adh;
        e = fmaxf(e, 0.2f * e);
        float alpha = __expf(e - mh) * invh;
        float4 v = ((const float4*)xl)[sn * 64 + lane];
        acc.x += alpha * v.x; acc.y += alpha * v.y;
        acc.z += alpha * v.z; acc.w += alpha * v.w;
    }
    float4 bv = ((const float4*)bias)[lane];
    acc.x += bv.x; acc.y += bv.y; acc.z += bv.z; acc.w += bv.w;
    // fused LN(256) + GELU
    float mu = wave_sum(acc.x + acc.y + acc.z + acc.w) * (1.0f / 256.0f);
    float dx = acc.x - mu, dy = acc.y - mu, dz = acc.z - mu, dw = acc.w - mu;
    float var = wave_sum(dx * dx + dy * dy + dz * dz + dw * dw) * (1.0f / 256.0f);
    float r = rsqrtf(var + LN_EPS);
    float4 gv = ((const float4*)lng)[lane];
    float4 bb = ((const float4*)lnb)[lane];
    float y0 = gelu_exact(dx * r * gv.x + bb.x);
    float y1 = gelu_exact(dy * r * gv.y + bb.y);
    float y2 = gelu_exact(dz * r * gv.z + bb.z);
    float y3 = gelu_exact(dw * r * gv.w + bb.w);
    if (LAYER == 0) {
        float4 o = {y0, y1, y2, y3};
        ((float4*)out)[node * 64 + lane] = o;
    } else {
        float4 idv = ((const float4*)identity)[node * 64 + lane];
        y0 += idv.x; y1 += idv.y; y2 += idv.z; y3 += idv.w;
        int b = batch[node];
        float* p = pooled + b * 256 + 4 * lane;
        atomicAdd(p + 0, y0); atomicAdd(p + 1, y1);
        atomicAdd(p + 2, y2); atomicAdd(p + 3, y3);
        if (lane == 0) atomicAdd(cnt + b, 1);
    }
}

// ---------------- pooled MLP + log_softmax: one wave per graph ----------------
__global__ void k_final(const float* __restrict__ pooled, const int* __restrict__ cnt,
                        const float* __restrict__ fc1W, const float* __restrict__ fc1b,
                        const float* __restrict__ fc2W, const float* __restrict__ fc2b,
                        float* __restrict__ out) {
    __shared__ float prow[4][256];
    __shared__ float zrow[4][64];
    int wid = threadIdx.x >> 6, lane = threadIdx.x & 63;
    int g = blockIdx.x * 4 + wid;
    float inv = 1.0f / fmaxf((float)cnt[g], 1.0f);
#pragma unroll
    for (int k = lane; k < 256; k += 64) prow[wid][k] = pooled[g * 256 + k] * inv;
    __syncthreads();
    float acc = fc1b[lane];
#pragma unroll 4
    for (int k = 0; k < 256; k++) acc += prow[wid][k] * fc1W[k * 64 + lane];
    zrow[wid][lane] = gelu_exact(acc);
    __syncthreads();
    float logit = fc2b[lane];
#pragma unroll 4
    for (int k = 0; k < 64; k++) logit += zrow[wid][k] * fc2W[k * 64 + lane];
    float mx = wave_max(logit);
    float se = wave_sum(__expf(logit - mx));
    out[g * NOUT + lane] = logit - mx - logf(se);
}

extern "C" void kernel_launch(void* const* d_in, const int* in_sizes, int n_in,
                              void* d_out, int out_size, void* d_ws, size_t ws_size,
                              hipStream_t stream) {
    const float* x     = (const float*)d_in[0];
    const int*   ei    = (const int*)d_in[1];
    const int*   batch = (const int*)d_in[2];
    const int*   gid   = (const int*)d_in[3];
    const float* gt    = (const float*)d_in[4];
    const float* inW   = (const float*)d_in[5];
    const float* inb   = (const float*)d_in[6];
    const float* inlng = (const float*)d_in[7];
    const float* inlnb = (const float*)d_in[8];
    const float* W0    = (const float*)d_in[9];
    const float* as0   = (const float*)d_in[10];
    const float* ad0   = (const float*)d_in[11];
    const float* b0    = (const float*)d_in[12];
    const float* ln0g  = (const float*)d_in[13];
    const float* ln0b  = (const float*)d_in[14];
    const float* W1    = (const float*)d_in[15];
    const float* as1   = (const float*)d_in[16];
    const float* ad1   = (const float*)d_in[17];
    const float* b1    = (const float*)d_in[18];
    const float* ln1g  = (const float*)d_in[19];
    const float* ln1b  = (const float*)d_in[20];
    const float* fc1W  = (const float*)d_in[21];
    const float* fc1b  = (const float*)d_in[22];
    const float* fc2W  = (const float*)d_in[23];
    const float* fc2b  = (const float*)d_in[24];
    float* out = (float*)d_out;

    char* ws = (char*)d_ws;
    size_t off = 0;
    auto alloc = [&](size_t bytes) {
        void* p = ws + off;
        off += (bytes + 255) / 256 * 256;
        return p;
    };
    float* h0     = (float*)alloc((size_t)N_NODES * 64 * 4);
    float* xl     = (float*)alloc((size_t)N_NODES * 256 * 4);
    float* als    = (float*)alloc((size_t)N_NODES * 4 * 4);
    float* ald    = (float*)alloc((size_t)N_NODES * 4 * 4);
    float* h1     = (float*)alloc((size_t)N_NODES * 256 * 4);
    int*   rowptr = (int*)alloc((size_t)(N_NODES + 1) * 4);
    int*   cursor = (int*)alloc((size_t)N_NODES * 4);
    int*   csr    = (int*)alloc((size_t)ETOT * 4);
    int*   deg    = (int*)alloc((size_t)N_NODES * 4);
    float* pooled = (float*)alloc((size_t)NGRAPH * 256 * 4);
    int*   cnt    = (int*)alloc((size_t)NGRAPH * 4);

    hipMemsetAsync(deg, 0, (size_t)N_NODES * 4, stream);
    hipMemsetAsync(pooled, 0, (size_t)NGRAPH * 256 * 4, stream);
    hipMemsetAsync(cnt, 0, (size_t)NGRAPH * 4, stream);

    int eb = (ETOT + 255) / 256;
    k_count<<<eb, 256, 0, stream>>>(ei, deg);
    k_scan<<<1, 1024, 0, stream>>>(deg, rowptr, cursor);
    k_fill<<<eb, 256, 0, stream>>>(ei, cursor, csr);
    k_proj_in<<<N_NODES / 4, 256, 0, stream>>>(x, gid, gt, inW, inb, inlng, inlnb, h0);
    k_proj_gat<64><<<N_NODES / 4, 256, 0, stream>>>(h0, W0, as0, ad0, xl, als, ald);
    k_gat_agg<0><<<N_NODES / 4, 256, 0, stream>>>(rowptr, csr, xl, als, ald, b0, ln0g, ln0b,
                                                  nullptr, h1, nullptr, nullptr, nullptr);
    k_proj_gat<256><<<N_NODES / 4, 256, 0, stream>>>(h1, W1, as1, ad1, xl, als, ald);
    k_gat_agg<1><<<N_NODES / 4, 256, 0, stream>>>(rowptr, csr, xl, als, ald, b1, ln1g, ln1b,
                                                  h1, nullptr, batch, pooled, cnt);
    k_final<<<NGRAPH / 4, 256, 0, stream>>>(pooled, cnt, fc1W, fc1b, fc2W, fc2b, out);
}

// Round 2
// 721.028 us; speedup vs baseline: 1.6304x; 1.6304x over previous
//
#include <hip/hip_runtime.h>
#include <math.h>

#define N_NODES 50000
#define N_EDGES 800000
#define ETOT (N_EDGES + N_NODES)
#define F_IN 128
#define HD 64
#define NHEAD 4
#define HC 256
#define NGRAPH 512
#define NOUT 64
#define LN_EPS 1e-5f

typedef __attribute__((ext_vector_type(8))) short bf16x8;
typedef __attribute__((ext_vector_type(4))) float f32x4;

__device__ __forceinline__ float wave_sum(float v) {
#pragma unroll
    for (int m = 1; m < 64; m <<= 1) v += __shfl_xor(v, m, 64);
    return v;
}
__device__ __forceinline__ float wave_max(float v) {
#pragma unroll
    for (int m = 1; m < 64; m <<= 1) v = fmaxf(v, __shfl_xor(v, m, 64));
    return v;
}
__device__ __forceinline__ float red16(float v) {
    v += __shfl_xor(v, 1, 64);
    v += __shfl_xor(v, 2, 64);
    v += __shfl_xor(v, 4, 64);
    v += __shfl_xor(v, 8, 64);
    return v;
}
__device__ __forceinline__ float gelu_exact(float x) {
    return 0.5f * x * (1.0f + erff(x * 0.70710678118654752f));
}
__device__ __forceinline__ unsigned short f2bf(float x) {
    unsigned int u = __float_as_uint(x);
    return (unsigned short)((u + 0x7fffu + ((u >> 16) & 1u)) >> 16);
}

// ---------------- CSR build ----------------
__global__ void k_count(const int* __restrict__ ei, int* __restrict__ deg) {
    int t = blockIdx.x * blockDim.x + threadIdx.x;
    if (t >= ETOT) return;
    int dst = (t < N_EDGES) ? ei[N_EDGES + t] : (t - N_EDGES);
    atomicAdd(deg + dst, 1);
}

__global__ void k_scan(const int* __restrict__ deg, int* __restrict__ rowptr,
                       int* __restrict__ cursor) {
    __shared__ int buf[1024];
    __shared__ int carry;
    if (threadIdx.x == 0) { carry = 0; rowptr[0] = 0; }
    __syncthreads();
    for (int base = 0; base < N_NODES; base += 1024) {
        int i = base + threadIdx.x;
        int v = (i < N_NODES) ? deg[i] : 0;
        buf[threadIdx.x] = v;
        __syncthreads();
        for (int off = 1; off < 1024; off <<= 1) {
            int t = (threadIdx.x >= off) ? buf[threadIdx.x - off] : 0;
            __syncthreads();
            buf[threadIdx.x] += t;
            __syncthreads();
        }
        if (i < N_NODES) {
            int incl = carry + buf[threadIdx.x];
            rowptr[i + 1] = incl;
            cursor[i] = incl - v;
        }
        __syncthreads();
        if (threadIdx.x == 1023) carry += buf[1023];
        __syncthreads();
    }
}

__global__ void k_fill(const int* __restrict__ ei, int* __restrict__ cursor,
                       int* __restrict__ csr) {
    int t = blockIdx.x * blockDim.x + threadIdx.x;
    if (t >= ETOT) return;
    int src, dst;
    if (t < N_EDGES) { src = ei[t]; dst = ei[N_EDGES + t]; }
    else             { src = t - N_EDGES; dst = src; }
    int p = atomicAdd(cursor + dst, 1);
    csr[p] = src;
}

// ---------------- prep: concat(x, group_emb) -> bf16 [N, 192] ----------------
__global__ void k_prep(const float* __restrict__ x, const int* __restrict__ gid,
                       const float* __restrict__ gt, unsigned short* __restrict__ Ain) {
    int wid = threadIdx.x >> 6, lane = threadIdx.x & 63;
    int node = blockIdx.x * 4 + wid;
    float f0 = x[node * F_IN + lane];
    float f1 = x[node * F_IN + 64 + lane];
    int g = gid[node];
    float f2 = gt[g * HD + lane];
    unsigned short* r = Ain + (size_t)node * 192;
    r[lane] = f2bf(f0);
    r[64 + lane] = f2bf(f1);
    r[128 + lane] = f2bf(f2);
}

// ---------------- pack W [K,N] f32 -> fragment-order bf16 [K/32][N/16][64][8] ----------------
__global__ void k_pack(const float* __restrict__ W, unsigned short* __restrict__ out,
                       int K, int N) {
    int tid = blockIdx.x * blockDim.x + threadIdx.x;
    int NB = N >> 4;
    int total = (K >> 5) * NB * 512;
    if (tid >= total) return;
    int i = tid & 7;
    int l = (tid >> 3) & 63;
    int t2 = tid >> 9;
    int nb = t2 % NB;
    int kt = t2 / NB;
    int k = kt * 32 + ((l >> 4) << 3) + i;
    int n = nb * 16 + (l & 15);
    out[tid] = f2bf(W[k * N + n]);
}

// ---------------- input projection (MFMA): [N,192]@[192,64] -> LN -> GELU -> bf16 ----------------
__global__ void k_proj_in_mma(const unsigned short* __restrict__ A,
                              const unsigned short* __restrict__ Wpk,
                              const float* __restrict__ inb, const float* __restrict__ lng,
                              const float* __restrict__ lnb, unsigned short* __restrict__ h0bf) {
    int wid = threadIdx.x >> 6, lane = threadIdx.x & 63;
    int m0 = blockIdx.x * 64 + wid * 16;
    if (m0 >= N_NODES) return;
    int g16 = lane >> 4, c16 = lane & 15;
    f32x4 acc[4] = {{0,0,0,0},{0,0,0,0},{0,0,0,0},{0,0,0,0}};
#pragma unroll
    for (int kt = 0; kt < 6; kt++) {
        bf16x8 a = *(const bf16x8*)(A + (size_t)(m0 + c16) * 192 + kt * 32 + g16 * 8);
#pragma unroll
        for (int nt = 0; nt < 4; nt++) {
            bf16x8 b = *(const bf16x8*)(Wpk + (((kt * 4 + nt) * 64 + lane) << 3));
            acc[nt] = __builtin_amdgcn_mfma_f32_16x16x32_bf16(a, b, acc[nt], 0, 0, 0);
        }
    }
    float bv[4], gv[4], bb[4];
#pragma unroll
    for (int nt = 0; nt < 4; nt++) {
        int c = nt * 16 + c16;
        bv[nt] = inb[c]; gv[nt] = lng[c]; bb[nt] = lnb[c];
    }
#pragma unroll
    for (int j = 0; j < 4; j++) {
        float d[4], s = 0.f;
#pragma unroll
        for (int nt = 0; nt < 4; nt++) { d[nt] = acc[nt][j] + bv[nt]; s += d[nt]; }
        float mu = red16(s) * (1.0f / 64.0f);
        float v = 0.f;
#pragma unroll
        for (int nt = 0; nt < 4; nt++) { d[nt] -= mu; v += d[nt] * d[nt]; }
        float r = rsqrtf(red16(v) * (1.0f / 64.0f) + LN_EPS);
        int row = m0 + g16 * 4 + j;
#pragma unroll
        for (int nt = 0; nt < 4; nt++) {
            float y = gelu_exact(d[nt] * r * gv[nt] + bb[nt]);
            h0bf[(size_t)row * 64 + nt * 16 + c16] = f2bf(y);
        }
    }
}

// ---------------- GAT projection (MFMA): xl = A@W [N,K]->[N,256], + attention logits ----------------
template <int KT>  // K/32
__global__ void k_proj_mma(const unsigned short* __restrict__ A,
                           const unsigned short* __restrict__ Wpk,
                           const float* __restrict__ as_, const float* __restrict__ ad_,
                           float* __restrict__ xl, float* __restrict__ als,
                           float* __restrict__ ald) {
    int wid = threadIdx.x >> 6, lane = threadIdx.x & 63;  // wid = head
    int m0 = blockIdx.x * 16;
    int g16 = lane >> 4, c16 = lane & 15;
    const int K = KT * 32;
    f32x4 acc[4] = {{0,0,0,0},{0,0,0,0},{0,0,0,0},{0,0,0,0}};
#pragma unroll
    for (int kt = 0; kt < KT; kt++) {
        bf16x8 a = *(const bf16x8*)(A + (size_t)(m0 + c16) * K + kt * 32 + g16 * 8);
#pragma unroll
        for (int nt = 0; nt < 4; nt++) {
            bf16x8 b = *(const bf16x8*)(Wpk + (((kt * 16 + wid * 4 + nt) * 64 + lane) << 3));
            acc[nt] = __builtin_amdgcn_mfma_f32_16x16x32_bf16(a, b, acc[nt], 0, 0, 0);
        }
    }
    float asv[4], adv[4];
#pragma unroll
    for (int nt = 0; nt < 4; nt++) {
        int c = wid * 64 + nt * 16 + c16;
        asv[nt] = as_[c]; adv[nt] = ad_[c];
    }
#pragma unroll
    for (int j = 0; j < 4; j++) {
        int row = m0 + g16 * 4 + j;
        float ps = 0.f, pd = 0.f;
#pragma unroll
        for (int nt = 0; nt < 4; nt++) {
            float v = acc[nt][j];
            xl[(size_t)row * 256 + wid * 64 + nt * 16 + c16] = v;
            ps += v * asv[nt]; pd += v * adv[nt];
        }
        ps = red16(ps); pd = red16(pd);
        if (c16 == 0) { als[row * 4 + wid] = ps; ald[row * 4 + wid] = pd; }
    }
}

// ---------------- GAT aggregation (pull, one wave per dst) + fused epilogue ----------------
template <int LAYER>
__global__ void k_gat_agg(const int* __restrict__ rowptr, const int* __restrict__ csr,
                          const float* __restrict__ xl, const float* __restrict__ als,
                          const float* __restrict__ ald, const float* __restrict__ bias,
                          const float* __restrict__ lng, const float* __restrict__ lnb,
                          const float* __restrict__ identity, float* __restrict__ out,
                          unsigned short* __restrict__ out_bf,
                          const int* __restrict__ batch, float* __restrict__ pooled,
                          int* __restrict__ cnt) {
    int wid = threadIdx.x >> 6, lane = threadIdx.x & 63;
    int node = blockIdx.x * 4 + wid;
    int start = rowptr[node], end = rowptr[node + 1];
    int head = lane >> 4;
    float4 adv = ((const float4*)ald)[node];
    float ad0 = adv.x, ad1 = adv.y, ad2 = adv.z, ad3 = adv.w;
    float m0 = -1e30f, m1 = -1e30f, m2 = -1e30f, m3 = -1e30f;
    float s0 = 0.f, s1 = 0.f, s2 = 0.f, s3 = 0.f;
    for (int k = start + lane; k < end; k += 64) {
        int sn = csr[k];
        float4 sv = ((const float4*)als)[sn];
        float e0 = sv.x + ad0; e0 = fmaxf(e0, 0.2f * e0);
        float e1 = sv.y + ad1; e1 = fmaxf(e1, 0.2f * e1);
        float e2 = sv.z + ad2; e2 = fmaxf(e2, 0.2f * e2);
        float e3 = sv.w + ad3; e3 = fmaxf(e3, 0.2f * e3);
        float n;
        n = fmaxf(m0, e0); s0 = s0 * __expf(m0 - n) + __expf(e0 - n); m0 = n;
        n = fmaxf(m1, e1); s1 = s1 * __expf(m1 - n) + __expf(e1 - n); m1 = n;
        n = fmaxf(m2, e2); s2 = s2 * __expf(m2 - n) + __expf(e2 - n); m2 = n;
        n = fmaxf(m3, e3); s3 = s3 * __expf(m3 - n) + __expf(e3 - n); m3 = n;
    }
#pragma unroll
    for (int msk = 1; msk < 64; msk <<= 1) {
        float o, t, n;
        o = __shfl_xor(m0, msk, 64); t = __shfl_xor(s0, msk, 64);
        n = fmaxf(m0, o); s0 = s0 * __expf(m0 - n) + t * __expf(o - n); m0 = n;
        o = __shfl_xor(m1, msk, 64); t = __shfl_xor(s1, msk, 64);
        n = fmaxf(m1, o); s1 = s1 * __expf(m1 - n) + t * __expf(o - n); m1 = n;
        o = __shfl_xor(m2, msk, 64); t = __shfl_xor(s2, msk, 64);
        n = fmaxf(m2, o); s2 = s2 * __expf(m2 - n) + t * __expf(o - n); m2 = n;
        o = __shfl_xor(m3, msk, 64); t = __shfl_xor(s3, msk, 64);
        n = fmaxf(m3, o); s3 = s3 * __expf(m3 - n) + t * __expf(o - n); m3 = n;
    }
    float mh  = head == 0 ? m0 : head == 1 ? m1 : head == 2 ? m2 : m3;
    float sh  = head == 0 ? s0 : head == 1 ? s1 : head == 2 ? s2 : s3;
    float adh = head == 0 ? ad0 : head == 1 ? ad1 : head == 2 ? ad2 : ad3;
    float invh = 1.0f / (sh + 1e-16f);
    float4 acc = {0.f, 0.f, 0.f, 0.f};
    for (int k = start; k < end; k++) {
        int sn = csr[k];
        float e = als[sn * 4 + head] + adh;
        e = fmaxf(e, 0.2f * e);
        float alpha = __expf(e - mh) * invh;
        float4 v = ((const float4*)xl)[(size_t)sn * 64 + lane];
        acc.x += alpha * v.x; acc.y += alpha * v.y;
        acc.z += alpha * v.z; acc.w += alpha * v.w;
    }
    float4 bv = ((const float4*)bias)[lane];
    acc.x += bv.x; acc.y += bv.y; acc.z += bv.z; acc.w += bv.w;
    float mu = wave_sum(acc.x + acc.y + acc.z + acc.w) * (1.0f / 256.0f);
    float dx = acc.x - mu, dy = acc.y - mu, dz = acc.z - mu, dw = acc.w - mu;
    float var = wave_sum(dx * dx + dy * dy + dz * dz + dw * dw) * (1.0f / 256.0f);
    float r = rsqrtf(var + LN_EPS);
    float4 gv = ((const float4*)lng)[lane];
    float4 bb = ((const float4*)lnb)[lane];
    float y0 = gelu_exact(dx * r * gv.x + bb.x);
    float y1 = gelu_exact(dy * r * gv.y + bb.y);
    float y2 = gelu_exact(dz * r * gv.z + bb.z);
    float y3 = gelu_exact(dw * r * gv.w + bb.w);
    if (LAYER == 0) {
        float4 o = {y0, y1, y2, y3};
        ((float4*)out)[(size_t)node * 64 + lane] = o;
        ushort4 ob = {f2bf(y0), f2bf(y1), f2bf(y2), f2bf(y3)};
        ((ushort4*)out_bf)[(size_t)node * 64 + lane] = ob;
    } else {
        float4 idv = ((const float4*)identity)[(size_t)node * 64 + lane];
        y0 += idv.x; y1 += idv.y; y2 += idv.z; y3 += idv.w;
        int b = batch[node];
        float* p = pooled + b * 256 + 4 * lane;
        atomicAdd(p + 0, y0); atomicAdd(p + 1, y1);
        atomicAdd(p + 2, y2); atomicAdd(p + 3, y3);
        if (lane == 0) atomicAdd(cnt + b, 1);
    }
}

// ---------------- pooled MLP + log_softmax: one wave per graph ----------------
__global__ void k_final(const float* __restrict__ pooled, const int* __restrict__ cnt,
                        const float* __restrict__ fc1W, const float* __restrict__ fc1b,
                        const float* __restrict__ fc2W, const float* __restrict__ fc2b,
                        float* __restrict__ out) {
    __shared__ float prow[4][256];
    __shared__ float zrow[4][64];
    int wid = threadIdx.x >> 6, lane = threadIdx.x & 63;
    int g = blockIdx.x * 4 + wid;
    float inv = 1.0f / fmaxf((float)cnt[g], 1.0f);
#pragma unroll
    for (int k = lane; k < 256; k += 64) prow[wid][k] = pooled[g * 256 + k] * inv;
    __syncthreads();
    float acc = fc1b[lane];
#pragma unroll 4
    for (int k = 0; k < 256; k++) acc += prow[wid][k] * fc1W[k * 64 + lane];
    zrow[wid][lane] = gelu_exact(acc);
    __syncthreads();
    float logit = fc2b[lane];
#pragma unroll 4
    for (int k = 0; k < 64; k++) logit += zrow[wid][k] * fc2W[k * 64 + lane];
    float mx = wave_max(logit);
    float se = wave_sum(__expf(logit - mx));
    out[g * NOUT + lane] = logit - mx - logf(se);
}

extern "C" void kernel_launch(void* const* d_in, const int* in_sizes, int n_in,
                              void* d_out, int out_size, void* d_ws, size_t ws_size,
                              hipStream_t stream) {
    const float* x     = (const float*)d_in[0];
    const int*   ei    = (const int*)d_in[1];
    const int*   batch = (const int*)d_in[2];
    const int*   gid   = (const int*)d_in[3];
    const float* gt    = (const float*)d_in[4];
    const float* inW   = (const float*)d_in[5];
    const float* inb   = (const float*)d_in[6];
    const float* inlng = (const float*)d_in[7];
    const float* inlnb = (const float*)d_in[8];
    const float* W0    = (const float*)d_in[9];
    const float* as0   = (const float*)d_in[10];
    const float* ad0   = (const float*)d_in[11];
    const float* b0    = (const float*)d_in[12];
    const float* ln0g  = (const float*)d_in[13];
    const float* ln0b  = (const float*)d_in[14];
    const float* W1    = (const float*)d_in[15];
    const float* as1   = (const float*)d_in[16];
    const float* ad1   = (const float*)d_in[17];
    const float* b1    = (const float*)d_in[18];
    const float* ln1g  = (const float*)d_in[19];
    const float* ln1b  = (const float*)d_in[20];
    const float* fc1W  = (const float*)d_in[21];
    const float* fc1b  = (const float*)d_in[22];
    const float* fc2W  = (const float*)d_in[23];
    const float* fc2b  = (const float*)d_in[24];
    float* out = (float*)d_out;

    char* ws = (char*)d_ws;
    size_t off = 0;
    auto alloc = [&](size_t bytes) {
        void* p = ws + off;
        off += (bytes + 255) / 256 * 256;
        return p;
    };
    unsigned short* Ain   = (unsigned short*)alloc((size_t)N_NODES * 192 * 2);
    unsigned short* h0bf  = (unsigned short*)alloc((size_t)N_NODES * 64 * 2);
    unsigned short* h1bf  = (unsigned short*)alloc((size_t)N_NODES * 256 * 2);
    unsigned short* inWpk = (unsigned short*)alloc((size_t)192 * 64 * 2);
    unsigned short* W0pk  = (unsigned short*)alloc((size_t)64 * 256 * 2);
    unsigned short* W1pk  = (unsigned short*)alloc((size_t)256 * 256 * 2);
    float* xl     = (float*)alloc((size_t)N_NODES * 256 * 4);
    float* als    = (float*)alloc((size_t)N_NODES * 4 * 4);
    float* ald    = (float*)alloc((size_t)N_NODES * 4 * 4);
    float* h1     = (float*)alloc((size_t)N_NODES * 256 * 4);
    int*   rowptr = (int*)alloc((size_t)(N_NODES + 1) * 4);
    int*   cursor = (int*)alloc((size_t)N_NODES * 4);
    int*   csr    = (int*)alloc((size_t)ETOT * 4);
    int*   deg    = (int*)alloc((size_t)N_NODES * 4);
    float* pooled = (float*)alloc((size_t)NGRAPH * 256 * 4);
    int*   cnt    = (int*)alloc((size_t)NGRAPH * 4);

    hipMemsetAsync(deg, 0, (size_t)N_NODES * 4, stream);
    hipMemsetAsync(pooled, 0, (size_t)NGRAPH * 256 * 4, stream);
    hipMemsetAsync(cnt, 0, (size_t)NGRAPH * 4, stream);

    int eb = (ETOT + 255) / 256;
    k_count<<<eb, 256, 0, stream>>>(ei, deg);
    k_scan<<<1, 1024, 0, stream>>>(deg, rowptr, cursor);
    k_fill<<<eb, 256, 0, stream>>>(ei, cursor, csr);

    k_prep<<<N_NODES / 4, 256, 0, stream>>>(x, gid, gt, Ain);
    k_pack<<<(192 * 64 + 255) / 256, 256, 0, stream>>>(inW, inWpk, 192, 64);
    k_pack<<<(64 * 256 + 255) / 256, 256, 0, stream>>>(W0, W0pk, 64, 256);
    k_pack<<<(256 * 256 + 255) / 256, 256, 0, stream>>>(W1, W1pk, 256, 256);

    k_proj_in_mma<<<(N_NODES + 63) / 64, 256, 0, stream>>>(Ain, inWpk, inb, inlng, inlnb, h0bf);
    k_proj_mma<2><<<N_NODES / 16, 256, 0, stream>>>(h0bf, W0pk, as0, ad0, xl, als, ald);
    k_gat_agg<0><<<N_NODES / 4, 256, 0, stream>>>(rowptr, csr, xl, als, ald, b0, ln0g, ln0b,
                                                  nullptr, h1, h1bf, nullptr, nullptr, nullptr);
    k_proj_mma<8><<<N_NODES / 16, 256, 0, stream>>>(h1bf, W1pk, as1, ad1, xl, als, ald);
    k_gat_agg<1><<<N_NODES / 4, 256, 0, stream>>>(rowptr, csr, xl, als, ald, b1, ln1g, ln1b,
                                                  h1, nullptr, nullptr, batch, pooled, cnt);
    k_final<<<NGRAPH / 4, 256, 0, stream>>>(pooled, cnt, fc1W, fc1b, fc2W, fc2b, out);
}

// Round 3
// 619.567 us; speedup vs baseline: 1.8975x; 1.1638x over previous
//
#include <hip/hip_runtime.h>
#include <math.h>

#define N_NODES 50000
#define N_EDGES 800000
#define ETOT (N_EDGES + N_NODES)
#define F_IN 128
#define HD 64
#define NHEAD 4
#define HC 256
#define NGRAPH 512
#define NOUT 64
#define LN_EPS 1e-5f

typedef __attribute__((ext_vector_type(8))) short bf16x8;
typedef __attribute__((ext_vector_type(4))) float f32x4;

__device__ __forceinline__ float wave_sum(float v) {
#pragma unroll
    for (int m = 1; m < 64; m <<= 1) v += __shfl_xor(v, m, 64);
    return v;
}
__device__ __forceinline__ float wave_max(float v) {
#pragma unroll
    for (int m = 1; m < 64; m <<= 1) v = fmaxf(v, __shfl_xor(v, m, 64));
    return v;
}
__device__ __forceinline__ float red16(float v) {
    v += __shfl_xor(v, 1, 64);
    v += __shfl_xor(v, 2, 64);
    v += __shfl_xor(v, 4, 64);
    v += __shfl_xor(v, 8, 64);
    return v;
}
__device__ __forceinline__ float gelu_exact(float x) {
    return 0.5f * x * (1.0f + erff(x * 0.70710678118654752f));
}
__device__ __forceinline__ unsigned short f2bf(float x) {
    unsigned int u = __float_as_uint(x);
    return (unsigned short)((u + 0x7fffu + ((u >> 16) & 1u)) >> 16);
}
__device__ __forceinline__ float bf2f(unsigned short u) {
    return __uint_as_float(((unsigned int)u) << 16);
}

// ---------------- CSR build ----------------
__global__ void k_count(const int* __restrict__ ei, int* __restrict__ deg) {
    int t = blockIdx.x * blockDim.x + threadIdx.x;
    if (t >= ETOT) return;
    int dst = (t < N_EDGES) ? ei[N_EDGES + t] : (t - N_EDGES);
    atomicAdd(deg + dst, 1);
}

__global__ void k_scan(const int* __restrict__ deg, int* __restrict__ rowptr,
                       int* __restrict__ cursor) {
    __shared__ int buf[1024];
    __shared__ int carry;
    if (threadIdx.x == 0) { carry = 0; rowptr[0] = 0; }
    __syncthreads();
    for (int base = 0; base < N_NODES; base += 1024) {
        int i = base + threadIdx.x;
        int v = (i < N_NODES) ? deg[i] : 0;
        buf[threadIdx.x] = v;
        __syncthreads();
        for (int off = 1; off < 1024; off <<= 1) {
            int t = (threadIdx.x >= off) ? buf[threadIdx.x - off] : 0;
            __syncthreads();
            buf[threadIdx.x] += t;
            __syncthreads();
        }
        if (i < N_NODES) {
            int incl = carry + buf[threadIdx.x];
            rowptr[i + 1] = incl;
            cursor[i] = incl - v;
        }
        __syncthreads();
        if (threadIdx.x == 1023) carry += buf[1023];
        __syncthreads();
    }
}

__global__ void k_fill(const int* __restrict__ ei, int* __restrict__ cursor,
                       int* __restrict__ csr) {
    int t = blockIdx.x * blockDim.x + threadIdx.x;
    if (t >= ETOT) return;
    int src, dst;
    if (t < N_EDGES) { src = ei[t]; dst = ei[N_EDGES + t]; }
    else             { src = t - N_EDGES; dst = src; }
    int p = atomicAdd(cursor + dst, 1);
    csr[p] = src;
}

// ---------------- prep: concat(x, group_emb) -> bf16 [N, 192] ----------------
__global__ void k_prep(const float* __restrict__ x, const int* __restrict__ gid,
                       const float* __restrict__ gt, unsigned short* __restrict__ Ain) {
    int wid = threadIdx.x >> 6, lane = threadIdx.x & 63;
    int node = blockIdx.x * 4 + wid;
    float f0 = x[node * F_IN + lane];
    float f1 = x[node * F_IN + 64 + lane];
    int g = gid[node];
    float f2 = gt[g * HD + lane];
    unsigned short* r = Ain + (size_t)node * 192;
    r[lane] = f2bf(f0);
    r[64 + lane] = f2bf(f1);
    r[128 + lane] = f2bf(f2);
}

// ---------------- pack W [K,N] f32 -> fragment-order bf16 [K/32][N/16][64][8] ----------------
__global__ void k_pack(const float* __restrict__ W, unsigned short* __restrict__ out,
                       int K, int N) {
    int tid = blockIdx.x * blockDim.x + threadIdx.x;
    int NB = N >> 4;
    int total = (K >> 5) * NB * 512;
    if (tid >= total) return;
    int i = tid & 7;
    int l = (tid >> 3) & 63;
    int t2 = tid >> 9;
    int nb = t2 % NB;
    int kt = t2 / NB;
    int k = kt * 32 + ((l >> 4) << 3) + i;
    int n = nb * 16 + (l & 15);
    out[tid] = f2bf(W[k * N + n]);
}

// ---------------- input projection (MFMA): [N,192]@[192,64] -> LN -> GELU -> bf16 ----------------
__global__ void k_proj_in_mma(const unsigned short* __restrict__ A,
                              const unsigned short* __restrict__ Wpk,
                              const float* __restrict__ inb, const float* __restrict__ lng,
                              const float* __restrict__ lnb, unsigned short* __restrict__ h0bf) {
    int wid = threadIdx.x >> 6, lane = threadIdx.x & 63;
    int m0 = blockIdx.x * 64 + wid * 16;
    if (m0 >= N_NODES) return;
    int g16 = lane >> 4, c16 = lane & 15;
    f32x4 acc[4] = {{0,0,0,0},{0,0,0,0},{0,0,0,0},{0,0,0,0}};
#pragma unroll
    for (int kt = 0; kt < 6; kt++) {
        bf16x8 a = *(const bf16x8*)(A + (size_t)(m0 + c16) * 192 + kt * 32 + g16 * 8);
#pragma unroll
        for (int nt = 0; nt < 4; nt++) {
            bf16x8 b = *(const bf16x8*)(Wpk + (((kt * 4 + nt) * 64 + lane) << 3));
            acc[nt] = __builtin_amdgcn_mfma_f32_16x16x32_bf16(a, b, acc[nt], 0, 0, 0);
        }
    }
    float bv[4], gv[4], bb[4];
#pragma unroll
    for (int nt = 0; nt < 4; nt++) {
        int c = nt * 16 + c16;
        bv[nt] = inb[c]; gv[nt] = lng[c]; bb[nt] = lnb[c];
    }
#pragma unroll
    for (int j = 0; j < 4; j++) {
        float d[4], s = 0.f;
#pragma unroll
        for (int nt = 0; nt < 4; nt++) { d[nt] = acc[nt][j] + bv[nt]; s += d[nt]; }
        float mu = red16(s) * (1.0f / 64.0f);
        float v = 0.f;
#pragma unroll
        for (int nt = 0; nt < 4; nt++) { d[nt] -= mu; v += d[nt] * d[nt]; }
        float r = rsqrtf(red16(v) * (1.0f / 64.0f) + LN_EPS);
        int row = m0 + g16 * 4 + j;
#pragma unroll
        for (int nt = 0; nt < 4; nt++) {
            float y = gelu_exact(d[nt] * r * gv[nt] + bb[nt]);
            h0bf[(size_t)row * 64 + nt * 16 + c16] = f2bf(y);
        }
    }
}

// ---------------- GAT projection (MFMA): xl(bf16) = A@W [N,K]->[N,256], + attention logits ----------------
template <int KT>  // K/32
__global__ void k_proj_mma(const unsigned short* __restrict__ A,
                           const unsigned short* __restrict__ Wpk,
                           const float* __restrict__ as_, const float* __restrict__ ad_,
                           unsigned short* __restrict__ xlbf, float* __restrict__ als,
                           float* __restrict__ ald) {
    int wid = threadIdx.x >> 6, lane = threadIdx.x & 63;  // wid = head
    int m0 = blockIdx.x * 16;
    int g16 = lane >> 4, c16 = lane & 15;
    const int K = KT * 32;
    f32x4 acc[4] = {{0,0,0,0},{0,0,0,0},{0,0,0,0},{0,0,0,0}};
#pragma unroll
    for (int kt = 0; kt < KT; kt++) {
        bf16x8 a = *(const bf16x8*)(A + (size_t)(m0 + c16) * K + kt * 32 + g16 * 8);
#pragma unroll
        for (int nt = 0; nt < 4; nt++) {
            bf16x8 b = *(const bf16x8*)(Wpk + (((kt * 16 + wid * 4 + nt) * 64 + lane) << 3));
            acc[nt] = __builtin_amdgcn_mfma_f32_16x16x32_bf16(a, b, acc[nt], 0, 0, 0);
        }
    }
    float asv[4], adv[4];
#pragma unroll
    for (int nt = 0; nt < 4; nt++) {
        int c = wid * 64 + nt * 16 + c16;
        asv[nt] = as_[c]; adv[nt] = ad_[c];
    }
#pragma unroll
    for (int j = 0; j < 4; j++) {
        int row = m0 + g16 * 4 + j;
        float ps = 0.f, pd = 0.f;
#pragma unroll
        for (int nt = 0; nt < 4; nt++) {
            float v = acc[nt][j];
            xlbf[(size_t)row * 256 + wid * 64 + nt * 16 + c16] = f2bf(v);
            ps += v * asv[nt]; pd += v * adv[nt];
        }
        ps = red16(ps); pd = red16(pd);
        if (c16 == 0) { als[row * 4 + wid] = ps; ald[row * 4 + wid] = pd; }
    }
}

// ---------------- GAT aggregation (pull, one wave per dst) + fused epilogue ----------------
template <int LAYER>
__global__ void k_gat_agg(const int* __restrict__ rowptr, const int* __restrict__ csr,
                          const unsigned short* __restrict__ xlbf, const float* __restrict__ als,
                          const float* __restrict__ ald, const float* __restrict__ bias,
                          const float* __restrict__ lng, const float* __restrict__ lnb,
                          const float* __restrict__ identity, float* __restrict__ out,
                          unsigned short* __restrict__ out_bf,
                          const int* __restrict__ batch, float* __restrict__ pooled,
                          int* __restrict__ cnt) {
    int wid = threadIdx.x >> 6, lane = threadIdx.x & 63;
    int node = blockIdx.x * 4 + wid;
    int start = rowptr[node], end = rowptr[node + 1];
    int head = lane >> 4;
    float4 adv = ((const float4*)ald)[node];
    float ad0 = adv.x, ad1 = adv.y, ad2 = adv.z, ad3 = adv.w;
    float m0 = -1e30f, m1 = -1e30f, m2 = -1e30f, m3 = -1e30f;
    float s0 = 0.f, s1 = 0.f, s2 = 0.f, s3 = 0.f;
    for (int k = start + lane; k < end; k += 64) {
        int sn = csr[k];
        float4 sv = ((const float4*)als)[sn];
        float e0 = sv.x + ad0; e0 = fmaxf(e0, 0.2f * e0);
        float e1 = sv.y + ad1; e1 = fmaxf(e1, 0.2f * e1);
        float e2 = sv.z + ad2; e2 = fmaxf(e2, 0.2f * e2);
        float e3 = sv.w + ad3; e3 = fmaxf(e3, 0.2f * e3);
        float n;
        n = fmaxf(m0, e0); s0 = s0 * __expf(m0 - n) + __expf(e0 - n); m0 = n;
        n = fmaxf(m1, e1); s1 = s1 * __expf(m1 - n) + __expf(e1 - n); m1 = n;
        n = fmaxf(m2, e2); s2 = s2 * __expf(m2 - n) + __expf(e2 - n); m2 = n;
        n = fmaxf(m3, e3); s3 = s3 * __expf(m3 - n) + __expf(e3 - n); m3 = n;
    }
#pragma unroll
    for (int msk = 1; msk < 64; msk <<= 1) {
        float o, t, n;
        o = __shfl_xor(m0, msk, 64); t = __shfl_xor(s0, msk, 64);
        n = fmaxf(m0, o); s0 = s0 * __expf(m0 - n) + t * __expf(o - n); m0 = n;
        o = __shfl_xor(m1, msk, 64); t = __shfl_xor(s1, msk, 64);
        n = fmaxf(m1, o); s1 = s1 * __expf(m1 - n) + t * __expf(o - n); m1 = n;
        o = __shfl_xor(m2, msk, 64); t = __shfl_xor(s2, msk, 64);
        n = fmaxf(m2, o); s2 = s2 * __expf(m2 - n) + t * __expf(o - n); m2 = n;
        o = __shfl_xor(m3, msk, 64); t = __shfl_xor(s3, msk, 64);
        n = fmaxf(m3, o); s3 = s3 * __expf(m3 - n) + t * __expf(o - n); m3 = n;
    }
    float mh  = head == 0 ? m0 : head == 1 ? m1 : head == 2 ? m2 : m3;
    float sh  = head == 0 ? s0 : head == 1 ? s1 : head == 2 ? s2 : s3;
    float adh = head == 0 ? ad0 : head == 1 ? ad1 : head == 2 ? ad2 : ad3;
    float invh = 1.0f / (sh + 1e-16f);

    const ushort4* xl4 = (const ushort4*)xlbf;
    float4 acc = {0.f, 0.f, 0.f, 0.f};
    int k = start;
    for (; k + 4 <= end; k += 4) {
        int sn0 = csr[k], sn1 = csr[k + 1], sn2 = csr[k + 2], sn3 = csr[k + 3];
        float e0 = als[sn0 * 4 + head] + adh;
        float e1 = als[sn1 * 4 + head] + adh;
        float e2 = als[sn2 * 4 + head] + adh;
        float e3 = als[sn3 * 4 + head] + adh;
        ushort4 v0 = xl4[(size_t)sn0 * 64 + lane];
        ushort4 v1 = xl4[(size_t)sn1 * 64 + lane];
        ushort4 v2 = xl4[(size_t)sn2 * 64 + lane];
        ushort4 v3 = xl4[(size_t)sn3 * 64 + lane];
        e0 = fmaxf(e0, 0.2f * e0); e1 = fmaxf(e1, 0.2f * e1);
        e2 = fmaxf(e2, 0.2f * e2); e3 = fmaxf(e3, 0.2f * e3);
        float a0 = __expf(e0 - mh) * invh;
        float a1 = __expf(e1 - mh) * invh;
        float a2 = __expf(e2 - mh) * invh;
        float a3 = __expf(e3 - mh) * invh;
        acc.x += a0 * bf2f(v0.x) + a1 * bf2f(v1.x) + a2 * bf2f(v2.x) + a3 * bf2f(v3.x);
        acc.y += a0 * bf2f(v0.y) + a1 * bf2f(v1.y) + a2 * bf2f(v2.y) + a3 * bf2f(v3.y);
        acc.z += a0 * bf2f(v0.z) + a1 * bf2f(v1.z) + a2 * bf2f(v2.z) + a3 * bf2f(v3.z);
        acc.w += a0 * bf2f(v0.w) + a1 * bf2f(v1.w) + a2 * bf2f(v2.w) + a3 * bf2f(v3.w);
    }
    for (; k < end; k++) {
        int sn = csr[k];
        float e = als[sn * 4 + head] + adh;
        e = fmaxf(e, 0.2f * e);
        float a = __expf(e - mh) * invh;
        ushort4 v = xl4[(size_t)sn * 64 + lane];
        acc.x += a * bf2f(v.x); acc.y += a * bf2f(v.y);
        acc.z += a * bf2f(v.z); acc.w += a * bf2f(v.w);
    }
    float4 bv = ((const float4*)bias)[lane];
    acc.x += bv.x; acc.y += bv.y; acc.z += bv.z; acc.w += bv.w;
    float mu = wave_sum(acc.x + acc.y + acc.z + acc.w) * (1.0f / 256.0f);
    float dx = acc.x - mu, dy = acc.y - mu, dz = acc.z - mu, dw = acc.w - mu;
    float var = wave_sum(dx * dx + dy * dy + dz * dz + dw * dw) * (1.0f / 256.0f);
    float r = rsqrtf(var + LN_EPS);
    float4 gv = ((const float4*)lng)[lane];
    float4 bb = ((const float4*)lnb)[lane];
    float y0 = gelu_exact(dx * r * gv.x + bb.x);
    float y1 = gelu_exact(dy * r * gv.y + bb.y);
    float y2 = gelu_exact(dz * r * gv.z + bb.z);
    float y3 = gelu_exact(dw * r * gv.w + bb.w);
    if (LAYER == 0) {
        float4 o = {y0, y1, y2, y3};
        ((float4*)out)[(size_t)node * 64 + lane] = o;
        ushort4 ob = {f2bf(y0), f2bf(y1), f2bf(y2), f2bf(y3)};
        ((ushort4*)out_bf)[(size_t)node * 64 + lane] = ob;
    } else {
        float4 idv = ((const float4*)identity)[(size_t)node * 64 + lane];
        y0 += idv.x; y1 += idv.y; y2 += idv.z; y3 += idv.w;
        int b = batch[node];
        float* p = pooled + b * 256 + 4 * lane;
        atomicAdd(p + 0, y0); atomicAdd(p + 1, y1);
        atomicAdd(p + 2, y2); atomicAdd(p + 3, y3);
        if (lane == 0) atomicAdd(cnt + b, 1);
    }
}

// ---------------- pooled MLP + log_softmax: one wave per graph ----------------
__global__ void k_final(const float* __restrict__ pooled, const int* __restrict__ cnt,
                        const float* __restrict__ fc1W, const float* __restrict__ fc1b,
                        const float* __restrict__ fc2W, const float* __restrict__ fc2b,
                        float* __restrict__ out) {
    __shared__ float prow[4][256];
    __shared__ float zrow[4][64];
    int wid = threadIdx.x >> 6, lane = threadIdx.x & 63;
    int g = blockIdx.x * 4 + wid;
    float inv = 1.0f / fmaxf((float)cnt[g], 1.0f);
#pragma unroll
    for (int k = lane; k < 256; k += 64) prow[wid][k] = pooled[g * 256 + k] * inv;
    __syncthreads();
    float acc = fc1b[lane];
#pragma unroll 4
    for (int k = 0; k < 256; k++) acc += prow[wid][k] * fc1W[k * 64 + lane];
    zrow[wid][lane] = gelu_exact(acc);
    __syncthreads();
    float logit = fc2b[lane];
#pragma unroll 4
    for (int k = 0; k < 64; k++) logit += zrow[wid][k] * fc2W[k * 64 + lane];
    float mx = wave_max(logit);
    float se = wave_sum(__expf(logit - mx));
    out[g * NOUT + lane] = logit - mx - logf(se);
}

extern "C" void kernel_launch(void* const* d_in, const int* in_sizes, int n_in,
                              void* d_out, int out_size, void* d_ws, size_t ws_size,
                              hipStream_t stream) {
    const float* x     = (const float*)d_in[0];
    const int*   ei    = (const int*)d_in[1];
    const int*   batch = (const int*)d_in[2];
    const int*   gid   = (const int*)d_in[3];
    const float* gt    = (const float*)d_in[4];
    const float* inW   = (const float*)d_in[5];
    const float* inb   = (const float*)d_in[6];
    const float* inlng = (const float*)d_in[7];
    const float* inlnb = (const float*)d_in[8];
    const float* W0    = (const float*)d_in[9];
    const float* as0   = (const float*)d_in[10];
    const float* ad0   = (const float*)d_in[11];
    const float* b0    = (const float*)d_in[12];
    const float* ln0g  = (const float*)d_in[13];
    const float* ln0b  = (const float*)d_in[14];
    const float* W1    = (const float*)d_in[15];
    const float* as1   = (const float*)d_in[16];
    const float* ad1   = (const float*)d_in[17];
    const float* b1    = (const float*)d_in[18];
    const float* ln1g  = (const float*)d_in[19];
    const float* ln1b  = (const float*)d_in[20];
    const float* fc1W  = (const float*)d_in[21];
    const float* fc1b  = (const float*)d_in[22];
    const float* fc2W  = (const float*)d_in[23];
    const float* fc2b  = (const float*)d_in[24];
    float* out = (float*)d_out;

    char* ws = (char*)d_ws;
    size_t off = 0;
    auto alloc = [&](size_t bytes) {
        void* p = ws + off;
        off += (bytes + 255) / 256 * 256;
        return p;
    };
    unsigned short* Ain   = (unsigned short*)alloc((size_t)N_NODES * 192 * 2);
    unsigned short* h0bf  = (unsigned short*)alloc((size_t)N_NODES * 64 * 2);
    unsigned short* h1bf  = (unsigned short*)alloc((size_t)N_NODES * 256 * 2);
    unsigned short* inWpk = (unsigned short*)alloc((size_t)192 * 64 * 2);
    unsigned short* W0pk  = (unsigned short*)alloc((size_t)64 * 256 * 2);
    unsigned short* W1pk  = (unsigned short*)alloc((size_t)256 * 256 * 2);
    unsigned short* xlbf  = (unsigned short*)alloc((size_t)N_NODES * 256 * 2);
    float* als    = (float*)alloc((size_t)N_NODES * 4 * 4);
    float* ald    = (float*)alloc((size_t)N_NODES * 4 * 4);
    float* h1     = (float*)alloc((size_t)N_NODES * 256 * 4);
    int*   rowptr = (int*)alloc((size_t)(N_NODES + 1) * 4);
    int*   cursor = (int*)alloc((size_t)N_NODES * 4);
    int*   csr    = (int*)alloc((size_t)ETOT * 4);
    int*   deg    = (int*)alloc((size_t)N_NODES * 4);
    float* pooled = (float*)alloc((size_t)NGRAPH * 256 * 4);
    int*   cnt    = (int*)alloc((size_t)NGRAPH * 4);

    hipMemsetAsync(deg, 0, (size_t)N_NODES * 4, stream);
    hipMemsetAsync(pooled, 0, (size_t)NGRAPH * 256 * 4, stream);
    hipMemsetAsync(cnt, 0, (size_t)NGRAPH * 4, stream);

    int eb = (ETOT + 255) / 256;
    k_count<<<eb, 256, 0, stream>>>(ei, deg);
    k_scan<<<1, 1024, 0, stream>>>(deg, rowptr, cursor);
    k_fill<<<eb, 256, 0, stream>>>(ei, cursor, csr);

    k_prep<<<N_NODES / 4, 256, 0, stream>>>(x, gid, gt, Ain);
    k_pack<<<(192 * 64 + 255) / 256, 256, 0, stream>>>(inW, inWpk, 192, 64);
    k_pack<<<(64 * 256 + 255) / 256, 256, 0, stream>>>(W0, W0pk, 64, 256);
    k_pack<<<(256 * 256 + 255) / 256, 256, 0, stream>>>(W1, W1pk, 256, 256);

    k_proj_in_mma<<<(N_NODES + 63) / 64, 256, 0, stream>>>(Ain, inWpk, inb, inlng, inlnb, h0bf);
    k_proj_mma<2><<<N_NODES / 16, 256, 0, stream>>>(h0bf, W0pk, as0, ad0, xlbf, als, ald);
    k_gat_agg<0><<<N_NODES / 4, 256, 0, stream>>>(rowptr, csr, xlbf, als, ald, b0, ln0g, ln0b,
                                                  nullptr, h1, h1bf, nullptr, nullptr, nullptr);
    k_proj_mma<8><<<N_NODES / 16, 256, 0, stream>>>(h1bf, W1pk, as1, ad1, xlbf, als, ald);
    k_gat_agg<1><<<N_NODES / 4, 256, 0, stream>>>(rowptr, csr, xlbf, als, ald, b1, ln1g, ln1b,
                                                  h1, nullptr, nullptr, batch, pooled, cnt);
    k_final<<<NGRAPH / 4, 256, 0, stream>>>(pooled, cnt, fc1W, fc1b, fc2W, fc2b, out);
}

// Round 4
// 520.537 us; speedup vs baseline: 2.2584x; 1.1902x over previous
//
#include <hip/hip_runtime.h>
#include <math.h>

#define N_NODES 50000
#define N_EDGES 800000
#define ETOT (N_EDGES + N_NODES)
#define F_IN 128
#define HD 64
#define NHEAD 4
#define HC 256
#define NGRAPH 512
#define NOUT 64
#define LN_EPS 1e-5f

typedef __attribute__((ext_vector_type(8))) short bf16x8;
typedef __attribute__((ext_vector_type(4))) float f32x4;

__device__ __forceinline__ float wave_sum(float v) {
#pragma unroll
    for (int m = 1; m < 64; m <<= 1) v += __shfl_xor(v, m, 64);
    return v;
}
__device__ __forceinline__ float wave_max(float v) {
#pragma unroll
    for (int m = 1; m < 64; m <<= 1) v = fmaxf(v, __shfl_xor(v, m, 64));
    return v;
}
__device__ __forceinline__ float red16(float v) {
    v += __shfl_xor(v, 1, 64);
    v += __shfl_xor(v, 2, 64);
    v += __shfl_xor(v, 4, 64);
    v += __shfl_xor(v, 8, 64);
    return v;
}
__device__ __forceinline__ float gelu_exact(float x) {
    return 0.5f * x * (1.0f + erff(x * 0.70710678118654752f));
}
__device__ __forceinline__ unsigned short f2bf(float x) {
    unsigned int u = __float_as_uint(x);
    return (unsigned short)((u + 0x7fffu + ((u >> 16) & 1u)) >> 16);
}
__device__ __forceinline__ float bf2f(unsigned short u) {
    return __uint_as_float(((unsigned int)u) << 16);
}

// ---------------- CSR build ----------------
__global__ void k_count(const int* __restrict__ ei, int* __restrict__ deg) {
    int t = blockIdx.x * blockDim.x + threadIdx.x;
    if (t >= ETOT) return;
    int dst = (t < N_EDGES) ? ei[N_EDGES + t] : (t - N_EDGES);
    atomicAdd(deg + dst, 1);
}

// single block, 1024 threads, shfl-based scan (3 barriers per 1024-chunk)
__global__ void k_scan(const int* __restrict__ deg, int* __restrict__ rowptr,
                       int* __restrict__ cursor) {
    __shared__ int wsum[16];
    __shared__ int chunk_total;
    int tid = threadIdx.x, wid = tid >> 6, lane = tid & 63;
    int carry = 0;
    if (tid == 0) rowptr[0] = 0;
    for (int base = 0; base < N_NODES; base += 1024) {
        int i = base + tid;
        int v = (i < N_NODES) ? deg[i] : 0;
        int incl = v;
#pragma unroll
        for (int off = 1; off < 64; off <<= 1) {
            int t = __shfl_up(incl, off, 64);
            if (lane >= off) incl += t;
        }
        if (lane == 63) wsum[wid] = incl;
        __syncthreads();
        if (wid == 0) {
            int wv = (lane < 16) ? wsum[lane] : 0;
            int wincl = wv;
#pragma unroll
            for (int off = 1; off < 16; off <<= 1) {
                int t = __shfl_up(wincl, off, 64);
                if (lane >= off) wincl += t;
            }
            if (lane < 16) wsum[lane] = wincl - wv;  // exclusive wave offset
            if (lane == 15) chunk_total = wincl;
        }
        __syncthreads();
        int total_incl = carry + wsum[wid] + incl;
        if (i < N_NODES) {
            rowptr[i + 1] = total_incl;
            cursor[i] = total_incl - v;
        }
        carry += chunk_total;
        __syncthreads();
    }
}

__global__ void k_fill(const int* __restrict__ ei, int* __restrict__ cursor,
                       int* __restrict__ csr) {
    int t = blockIdx.x * blockDim.x + threadIdx.x;
    if (t >= ETOT) return;
    int src, dst;
    if (t < N_EDGES) { src = ei[t]; dst = ei[N_EDGES + t]; }
    else             { src = t - N_EDGES; dst = src; }
    int p = atomicAdd(cursor + dst, 1);
    csr[p] = src;
}

// ---------------- prep: concat(x, group_emb) -> bf16 [N, 192] ----------------
__global__ void k_prep(const float* __restrict__ x, const int* __restrict__ gid,
                       const float* __restrict__ gt, unsigned short* __restrict__ Ain) {
    int wid = threadIdx.x >> 6, lane = threadIdx.x & 63;
    int node = blockIdx.x * 4 + wid;
    float f0 = x[node * F_IN + lane];
    float f1 = x[node * F_IN + 64 + lane];
    int g = gid[node];
    float f2 = gt[g * HD + lane];
    unsigned short* r = Ain + (size_t)node * 192;
    r[lane] = f2bf(f0);
    r[64 + lane] = f2bf(f1);
    r[128 + lane] = f2bf(f2);
}

// ---------------- pack W [K,N] f32 -> fragment-order bf16 [K/32][N/16][64][8] ----------------
__global__ void k_pack(const float* __restrict__ W, unsigned short* __restrict__ out,
                       int K, int N) {
    int tid = blockIdx.x * blockDim.x + threadIdx.x;
    int NB = N >> 4;
    int total = (K >> 5) * NB * 512;
    if (tid >= total) return;
    int i = tid & 7;
    int l = (tid >> 3) & 63;
    int t2 = tid >> 9;
    int nb = t2 % NB;
    int kt = t2 / NB;
    int k = kt * 32 + ((l >> 4) << 3) + i;
    int n = nb * 16 + (l & 15);
    out[tid] = f2bf(W[k * N + n]);
}

// ---------------- input projection (MFMA): [N,192]@[192,64] -> LN -> GELU -> bf16 ----------------
__global__ void k_proj_in_mma(const unsigned short* __restrict__ A,
                              const unsigned short* __restrict__ Wpk,
                              const float* __restrict__ inb, const float* __restrict__ lng,
                              const float* __restrict__ lnb, unsigned short* __restrict__ h0bf) {
    int wid = threadIdx.x >> 6, lane = threadIdx.x & 63;
    int m0 = blockIdx.x * 64 + wid * 16;
    if (m0 >= N_NODES) return;
    int g16 = lane >> 4, c16 = lane & 15;
    f32x4 acc[4] = {{0,0,0,0},{0,0,0,0},{0,0,0,0},{0,0,0,0}};
#pragma unroll
    for (int kt = 0; kt < 6; kt++) {
        bf16x8 a = *(const bf16x8*)(A + (size_t)(m0 + c16) * 192 + kt * 32 + g16 * 8);
#pragma unroll
        for (int nt = 0; nt < 4; nt++) {
            bf16x8 b = *(const bf16x8*)(Wpk + (((kt * 4 + nt) * 64 + lane) << 3));
            acc[nt] = __builtin_amdgcn_mfma_f32_16x16x32_bf16(a, b, acc[nt], 0, 0, 0);
        }
    }
    float bv[4], gv[4], bb[4];
#pragma unroll
    for (int nt = 0; nt < 4; nt++) {
        int c = nt * 16 + c16;
        bv[nt] = inb[c]; gv[nt] = lng[c]; bb[nt] = lnb[c];
    }
#pragma unroll
    for (int j = 0; j < 4; j++) {
        float d[4], s = 0.f;
#pragma unroll
        for (int nt = 0; nt < 4; nt++) { d[nt] = acc[nt][j] + bv[nt]; s += d[nt]; }
        float mu = red16(s) * (1.0f / 64.0f);
        float v = 0.f;
#pragma unroll
        for (int nt = 0; nt < 4; nt++) { d[nt] -= mu; v += d[nt] * d[nt]; }
        float r = rsqrtf(red16(v) * (1.0f / 64.0f) + LN_EPS);
        int row = m0 + g16 * 4 + j;
#pragma unroll
        for (int nt = 0; nt < 4; nt++) {
            float y = gelu_exact(d[nt] * r * gv[nt] + bb[nt]);
            h0bf[(size_t)row * 64 + nt * 16 + c16] = f2bf(y);
        }
    }
}

// ---------------- GAT projection (MFMA): xl(bf16) = A@W [N,K]->[N,256], + attention logits ----------------
template <int KT>  // K/32
__global__ void k_proj_mma(const unsigned short* __restrict__ A,
                           const unsigned short* __restrict__ Wpk,
                           const float* __restrict__ as_, const float* __restrict__ ad_,
                           unsigned short* __restrict__ xlbf, float* __restrict__ als,
                           float* __restrict__ ald) {
    int wid = threadIdx.x >> 6, lane = threadIdx.x & 63;  // wid = head
    int m0 = blockIdx.x * 16;
    int g16 = lane >> 4, c16 = lane & 15;
    const int K = KT * 32;
    f32x4 acc[4] = {{0,0,0,0},{0,0,0,0},{0,0,0,0},{0,0,0,0}};
#pragma unroll
    for (int kt = 0; kt < KT; kt++) {
        bf16x8 a = *(const bf16x8*)(A + (size_t)(m0 + c16) * K + kt * 32 + g16 * 8);
#pragma unroll
        for (int nt = 0; nt < 4; nt++) {
            bf16x8 b = *(const bf16x8*)(Wpk + (((kt * 16 + wid * 4 + nt) * 64 + lane) << 3));
            acc[nt] = __builtin_amdgcn_mfma_f32_16x16x32_bf16(a, b, acc[nt], 0, 0, 0);
        }
    }
    float asv[4], adv[4];
#pragma unroll
    for (int nt = 0; nt < 4; nt++) {
        int c = wid * 64 + nt * 16 + c16;
        asv[nt] = as_[c]; adv[nt] = ad_[c];
    }
#pragma unroll
    for (int j = 0; j < 4; j++) {
        int row = m0 + g16 * 4 + j;
        float ps = 0.f, pd = 0.f;
#pragma unroll
        for (int nt = 0; nt < 4; nt++) {
            float v = acc[nt][j];
            xlbf[(size_t)row * 256 + wid * 64 + nt * 16 + c16] = f2bf(v);
            ps += v * asv[nt]; pd += v * adv[nt];
        }
        ps = red16(ps); pd = red16(pd);
        if (c16 == 0) { als[row * 4 + wid] = ps; ald[row * 4 + wid] = pd; }
    }
}

// ---------------- GAT aggregation: 2 waves per dst node (edge-range split) ----------------
template <int LAYER>
__global__ void k_gat_agg(const int* __restrict__ rowptr, const int* __restrict__ csr,
                          const unsigned short* __restrict__ xlbf, const float* __restrict__ als,
                          const float* __restrict__ ald, const float* __restrict__ bias,
                          const float* __restrict__ lng, const float* __restrict__ lnb,
                          const unsigned short* __restrict__ identity_bf,
                          unsigned short* __restrict__ out_bf,
                          const int* __restrict__ batch, float* __restrict__ pooled,
                          int* __restrict__ cnt) {
    __shared__ float4 lacc[2][64];
    __shared__ float4 lyout[2][64];
    __shared__ int lbatch[2];
    int wid = threadIdx.x >> 6, lane = threadIdx.x & 63;
    int nloc = wid >> 1, half = wid & 1;
    int node = blockIdx.x * 2 + nloc;
    int start = rowptr[node], end = rowptr[node + 1];
    int head = lane >> 4;
    float4 adv = ((const float4*)ald)[node];
    float ad0 = adv.x, ad1 = adv.y, ad2 = adv.z, ad3 = adv.w;
    float m0 = -1e30f, m1 = -1e30f, m2 = -1e30f, m3 = -1e30f;
    float s0 = 0.f, s1 = 0.f, s2 = 0.f, s3 = 0.f;
    // pass 1 (duplicated in both waves of the node; identical result)
    for (int k = start + lane; k < end; k += 64) {
        int sn = csr[k];
        float4 sv = ((const float4*)als)[sn];
        float e0 = sv.x + ad0; e0 = fmaxf(e0, 0.2f * e0);
        float e1 = sv.y + ad1; e1 = fmaxf(e1, 0.2f * e1);
        float e2 = sv.z + ad2; e2 = fmaxf(e2, 0.2f * e2);
        float e3 = sv.w + ad3; e3 = fmaxf(e3, 0.2f * e3);
        float n;
        n = fmaxf(m0, e0); s0 = s0 * __expf(m0 - n) + __expf(e0 - n); m0 = n;
        n = fmaxf(m1, e1); s1 = s1 * __expf(m1 - n) + __expf(e1 - n); m1 = n;
        n = fmaxf(m2, e2); s2 = s2 * __expf(m2 - n) + __expf(e2 - n); m2 = n;
        n = fmaxf(m3, e3); s3 = s3 * __expf(m3 - n) + __expf(e3 - n); m3 = n;
    }
#pragma unroll
    for (int msk = 1; msk < 64; msk <<= 1) {
        float o, t, n;
        o = __shfl_xor(m0, msk, 64); t = __shfl_xor(s0, msk, 64);
        n = fmaxf(m0, o); s0 = s0 * __expf(m0 - n) + t * __expf(o - n); m0 = n;
        o = __shfl_xor(m1, msk, 64); t = __shfl_xor(s1, msk, 64);
        n = fmaxf(m1, o); s1 = s1 * __expf(m1 - n) + t * __expf(o - n); m1 = n;
        o = __shfl_xor(m2, msk, 64); t = __shfl_xor(s2, msk, 64);
        n = fmaxf(m2, o); s2 = s2 * __expf(m2 - n) + t * __expf(o - n); m2 = n;
        o = __shfl_xor(m3, msk, 64); t = __shfl_xor(s3, msk, 64);
        n = fmaxf(m3, o); s3 = s3 * __expf(m3 - n) + t * __expf(o - n); m3 = n;
    }
    float mh  = head == 0 ? m0 : head == 1 ? m1 : head == 2 ? m2 : m3;
    float sh  = head == 0 ? s0 : head == 1 ? s1 : head == 2 ? s2 : s3;
    float adh = head == 0 ? ad0 : head == 1 ? ad1 : head == 2 ? ad2 : ad3;
    float invh = 1.0f / (sh + 1e-16f);

    // pass 2: each wave takes half the edge range (halved serial chain, 2x misses in flight)
    int cntE = end - start;
    int mid = start + ((cntE + 1) >> 1);
    int k0 = half ? mid : start;
    int k1 = half ? end : mid;
    const ushort4* xl4 = (const ushort4*)xlbf;
    float4 acc = {0.f, 0.f, 0.f, 0.f};
    int k = k0;
    for (; k + 4 <= k1; k += 4) {
        int sn0 = csr[k], sn1 = csr[k + 1], sn2 = csr[k + 2], sn3 = csr[k + 3];
        float e0 = als[sn0 * 4 + head] + adh;
        float e1 = als[sn1 * 4 + head] + adh;
        float e2 = als[sn2 * 4 + head] + adh;
        float e3 = als[sn3 * 4 + head] + adh;
        ushort4 v0 = xl4[(size_t)sn0 * 64 + lane];
        ushort4 v1 = xl4[(size_t)sn1 * 64 + lane];
        ushort4 v2 = xl4[(size_t)sn2 * 64 + lane];
        ushort4 v3 = xl4[(size_t)sn3 * 64 + lane];
        e0 = fmaxf(e0, 0.2f * e0); e1 = fmaxf(e1, 0.2f * e1);
        e2 = fmaxf(e2, 0.2f * e2); e3 = fmaxf(e3, 0.2f * e3);
        float a0 = __expf(e0 - mh) * invh;
        float a1 = __expf(e1 - mh) * invh;
        float a2 = __expf(e2 - mh) * invh;
        float a3 = __expf(e3 - mh) * invh;
        acc.x += a0 * bf2f(v0.x) + a1 * bf2f(v1.x) + a2 * bf2f(v2.x) + a3 * bf2f(v3.x);
        acc.y += a0 * bf2f(v0.y) + a1 * bf2f(v1.y) + a2 * bf2f(v2.y) + a3 * bf2f(v3.y);
        acc.z += a0 * bf2f(v0.z) + a1 * bf2f(v1.z) + a2 * bf2f(v2.z) + a3 * bf2f(v3.z);
        acc.w += a0 * bf2f(v0.w) + a1 * bf2f(v1.w) + a2 * bf2f(v2.w) + a3 * bf2f(v3.w);
    }
    for (; k < k1; k++) {
        int sn = csr[k];
        float e = als[sn * 4 + head] + adh;
        e = fmaxf(e, 0.2f * e);
        float a = __expf(e - mh) * invh;
        ushort4 v = xl4[(size_t)sn * 64 + lane];
        acc.x += a * bf2f(v.x); acc.y += a * bf2f(v.y);
        acc.z += a * bf2f(v.z); acc.w += a * bf2f(v.w);
    }
    if (half) lacc[nloc][lane] = acc;
    __syncthreads();
    if (!half) {
        float4 p = lacc[nloc][lane];
        acc.x += p.x; acc.y += p.y; acc.z += p.z; acc.w += p.w;
        float4 bv = ((const float4*)bias)[lane];
        acc.x += bv.x; acc.y += bv.y; acc.z += bv.z; acc.w += bv.w;
        float mu = wave_sum(acc.x + acc.y + acc.z + acc.w) * (1.0f / 256.0f);
        float dx = acc.x - mu, dy = acc.y - mu, dz = acc.z - mu, dw = acc.w - mu;
        float var = wave_sum(dx * dx + dy * dy + dz * dz + dw * dw) * (1.0f / 256.0f);
        float r = rsqrtf(var + LN_EPS);
        float4 gv = ((const float4*)lng)[lane];
        float4 bb = ((const float4*)lnb)[lane];
        float y0 = gelu_exact(dx * r * gv.x + bb.x);
        float y1 = gelu_exact(dy * r * gv.y + bb.y);
        float y2 = gelu_exact(dz * r * gv.z + bb.z);
        float y3 = gelu_exact(dw * r * gv.w + bb.w);
        if (LAYER == 0) {
            ushort4 ob = {f2bf(y0), f2bf(y1), f2bf(y2), f2bf(y3)};
            ((ushort4*)out_bf)[(size_t)node * 64 + lane] = ob;
        } else {
            ushort4 idv = ((const ushort4*)identity_bf)[(size_t)node * 64 + lane];
            float4 y = {y0 + bf2f(idv.x), y1 + bf2f(idv.y),
                        y2 + bf2f(idv.z), y3 + bf2f(idv.w)};
            lyout[nloc][lane] = y;
            if (lane == 0) lbatch[nloc] = batch[node];
        }
    }
    if (LAYER == 1) {
        __syncthreads();
        if (wid == 0) {
            int g0 = lbatch[0], g1 = lbatch[1];
            float4 a = lyout[0][lane], b = lyout[1][lane];
            float* p0 = pooled + (size_t)g0 * 256 + 4 * lane;
            if (g0 == g1) {
                atomicAdd(p0 + 0, a.x + b.x); atomicAdd(p0 + 1, a.y + b.y);
                atomicAdd(p0 + 2, a.z + b.z); atomicAdd(p0 + 3, a.w + b.w);
                if (lane == 0) atomicAdd(cnt + g0, 2);
            } else {
                float* p1 = pooled + (size_t)g1 * 256 + 4 * lane;
                atomicAdd(p0 + 0, a.x); atomicAdd(p0 + 1, a.y);
                atomicAdd(p0 + 2, a.z); atomicAdd(p0 + 3, a.w);
                atomicAdd(p1 + 0, b.x); atomicAdd(p1 + 1, b.y);
                atomicAdd(p1 + 2, b.z); atomicAdd(p1 + 3, b.w);
                if (lane == 0) { atomicAdd(cnt + g0, 1); atomicAdd(cnt + g1, 1); }
            }
        }
    }
}

// ---------------- pooled MLP + log_softmax: one wave per graph ----------------
__global__ void k_final(const float* __restrict__ pooled, const int* __restrict__ cnt,
                        const float* __restrict__ fc1W, const float* __restrict__ fc1b,
                        const float* __restrict__ fc2W, const float* __restrict__ fc2b,
                        float* __restrict__ out) {
    __shared__ float prow[4][256];
    __shared__ float zrow[4][64];
    int wid = threadIdx.x >> 6, lane = threadIdx.x & 63;
    int g = blockIdx.x * 4 + wid;
    float inv = 1.0f / fmaxf((float)cnt[g], 1.0f);
#pragma unroll
    for (int k = lane; k < 256; k += 64) prow[wid][k] = pooled[g * 256 + k] * inv;
    __syncthreads();
    float acc = fc1b[lane];
#pragma unroll 4
    for (int k = 0; k < 256; k++) acc += prow[wid][k] * fc1W[k * 64 + lane];
    zrow[wid][lane] = gelu_exact(acc);
    __syncthreads();
    float logit = fc2b[lane];
#pragma unroll 4
    for (int k = 0; k < 64; k++) logit += zrow[wid][k] * fc2W[k * 64 + lane];
    float mx = wave_max(logit);
    float se = wave_sum(__expf(logit - mx));
    out[g * NOUT + lane] = logit - mx - logf(se);
}

extern "C" void kernel_launch(void* const* d_in, const int* in_sizes, int n_in,
                              void* d_out, int out_size, void* d_ws, size_t ws_size,
                              hipStream_t stream) {
    const float* x     = (const float*)d_in[0];
    const int*   ei    = (const int*)d_in[1];
    const int*   batch = (const int*)d_in[2];
    const int*   gid   = (const int*)d_in[3];
    const float* gt    = (const float*)d_in[4];
    const float* inW   = (const float*)d_in[5];
    const float* inb   = (const float*)d_in[6];
    const float* inlng = (const float*)d_in[7];
    const float* inlnb = (const float*)d_in[8];
    const float* W0    = (const float*)d_in[9];
    const float* as0   = (const float*)d_in[10];
    const float* ad0   = (const float*)d_in[11];
    const float* b0    = (const float*)d_in[12];
    const float* ln0g  = (const float*)d_in[13];
    const float* ln0b  = (const float*)d_in[14];
    const float* W1    = (const float*)d_in[15];
    const float* as1   = (const float*)d_in[16];
    const float* ad1   = (const float*)d_in[17];
    const float* b1    = (const float*)d_in[18];
    const float* ln1g  = (const float*)d_in[19];
    const float* ln1b  = (const float*)d_in[20];
    const float* fc1W  = (const float*)d_in[21];
    const float* fc1b  = (const float*)d_in[22];
    const float* fc2W  = (const float*)d_in[23];
    const float* fc2b  = (const float*)d_in[24];
    float* out = (float*)d_out;

    char* ws = (char*)d_ws;
    size_t off = 0;
    auto alloc = [&](size_t bytes) {
        void* p = ws + off;
        off += (bytes + 255) / 256 * 256;
        return p;
    };
    unsigned short* Ain   = (unsigned short*)alloc((size_t)N_NODES * 192 * 2);
    unsigned short* h0bf  = (unsigned short*)alloc((size_t)N_NODES * 64 * 2);
    unsigned short* h1bf  = (unsigned short*)alloc((size_t)N_NODES * 256 * 2);
    unsigned short* inWpk = (unsigned short*)alloc((size_t)192 * 64 * 2);
    unsigned short* W0pk  = (unsigned short*)alloc((size_t)64 * 256 * 2);
    unsigned short* W1pk  = (unsigned short*)alloc((size_t)256 * 256 * 2);
    unsigned short* xlbf  = (unsigned short*)alloc((size_t)N_NODES * 256 * 2);
    float* als    = (float*)alloc((size_t)N_NODES * 4 * 4);
    float* ald    = (float*)alloc((size_t)N_NODES * 4 * 4);
    int*   rowptr = (int*)alloc((size_t)(N_NODES + 1) * 4);
    int*   cursor = (int*)alloc((size_t)N_NODES * 4);
    int*   csr    = (int*)alloc((size_t)ETOT * 4);
    int*   deg    = (int*)alloc((size_t)N_NODES * 4);
    float* pooled = (float*)alloc((size_t)NGRAPH * 256 * 4);
    int*   cnt    = (int*)alloc((size_t)NGRAPH * 4);

    hipMemsetAsync(deg, 0, (size_t)N_NODES * 4, stream);
    hipMemsetAsync(pooled, 0, (size_t)NGRAPH * 256 * 4, stream);
    hipMemsetAsync(cnt, 0, (size_t)NGRAPH * 4, stream);

    int eb = (ETOT + 255) / 256;
    k_count<<<eb, 256, 0, stream>>>(ei, deg);
    k_scan<<<1, 1024, 0, stream>>>(deg, rowptr, cursor);
    k_fill<<<eb, 256, 0, stream>>>(ei, cursor, csr);

    k_prep<<<N_NODES / 4, 256, 0, stream>>>(x, gid, gt, Ain);
    k_pack<<<(192 * 64 + 255) / 256, 256, 0, stream>>>(inW, inWpk, 192, 64);
    k_pack<<<(64 * 256 + 255) / 256, 256, 0, stream>>>(W0, W0pk, 64, 256);
    k_pack<<<(256 * 256 + 255) / 256, 256, 0, stream>>>(W1, W1pk, 256, 256);

    k_proj_in_mma<<<(N_NODES + 63) / 64, 256, 0, stream>>>(Ain, inWpk, inb, inlng, inlnb, h0bf);
    k_proj_mma<2><<<N_NODES / 16, 256, 0, stream>>>(h0bf, W0pk, as0, ad0, xlbf, als, ald);
    k_gat_agg<0><<<N_NODES / 2, 256, 0, stream>>>(rowptr, csr, xlbf, als, ald, b0, ln0g, ln0b,
                                                  nullptr, h1bf, nullptr, nullptr, nullptr);
    k_proj_mma<8><<<N_NODES / 16, 256, 0, stream>>>(h1bf, W1pk, as1, ad1, xlbf, als, ald);
    k_gat_agg<1><<<N_NODES / 2, 256, 0, stream>>>(rowptr, csr, xlbf, als, ald, b1, ln1g, ln1b,
                                                  h1bf, nullptr, batch, pooled, cnt);
    k_final<<<NGRAPH / 4, 256, 0, stream>>>(pooled, cnt, fc1W, fc1b, fc2W, fc2b, out);
}